// Round 4
// baseline (14080.730 us; speedup 1.0000x reference)
//
#include <hip/hip_runtime.h>
#include <stdint.h>

// MyVanillaRNN: B=64, T=512, INPUT=512, HIDDEN=1024
// out = concat( pre[B,T,H] (f32), h_final[B,H] (f32) )

typedef __attribute__((ext_vector_type(8))) short bf16x8;
typedef __attribute__((ext_vector_type(4))) float f32x4;

__device__ __forceinline__ uint32_t f2bf(float f) {
    union { float f; uint32_t u; } v; v.f = f;
    return (v.u + 0x7FFFu + ((v.u >> 16) & 1u)) >> 16;   // RNE
}
__device__ __forceinline__ uint32_t pack2bf(float a, float b) {
    return f2bf(a) | (f2bf(b) << 16);
}
__device__ __forceinline__ float fast_tanh(float x) {
    const float xc = fminf(fmaxf(x, -15.f), 15.f);
    const float e  = __expf(2.f * xc);
    return (e - 1.f) * __builtin_amdgcn_rcpf(e + 1.f);
}
// L1-bypassing load (may hit local L2). Freshness cross-XCD not guaranteed ->
// fallback to agent-scope loads after a few rounds for liveness.
__device__ __forceinline__ uint32_t ld_sc0(const uint32_t* p) {
    uint32_t v;
    asm volatile("global_load_dword %0, %1, off sc0"
                 : "=v"(v) : "v"((uint64_t)(uintptr_t)p));
    return v;
}

// ---------------------------------------------------------------------------
// Phase 1: out[m][n] = sum_k x[m][k]*Wx[n][k] + bx[n] + bh[n]
// M=32768, N=1024, K=512.  128x128 tile, BK=64, 4 waves, bf16 MFMA.
// ---------------------------------------------------------------------------
__global__ __launch_bounds__(256) void xproj_gemm(
    const float* __restrict__ x, const float* __restrict__ Wx,
    const float* __restrict__ bx, const float* __restrict__ bh,
    float* __restrict__ out)
{
    __shared__ __align__(16) uint8_t Ab[128 * 128];
    __shared__ __align__(16) uint8_t Bb[128 * 128];

    const int tid  = threadIdx.x;
    const int lane = tid & 63;
    const int wid  = tid >> 6;
    const int wm = wid >> 1, wn = wid & 1;
    const int m0 = (int)(blockIdx.x >> 3) * 128;
    const int n0 = (int)(blockIdx.x & 7) * 128;

    f32x4 acc[4][4];
    #pragma unroll
    for (int i = 0; i < 4; ++i)
        #pragma unroll
        for (int j = 0; j < 4; ++j) acc[i][j] = (f32x4){0.f, 0.f, 0.f, 0.f};

    const int sr = tid >> 4;
    const int sk = (tid & 15) << 2;

    for (int k0 = 0; k0 < 512; k0 += 64) {
        __syncthreads();
        #pragma unroll
        for (int p = 0; p < 8; ++p) {
            const int r = sr + p * 16;
            const float4 a = *(const float4*)(x  + (size_t)(m0 + r) * 512 + k0 + sk);
            const float4 b = *(const float4*)(Wx + (size_t)(n0 + r) * 512 + k0 + sk);
            const int byo = r * 128 + ((sk << 1) ^ ((r & 7) << 4));
            *(uint2*)(Ab + byo) = make_uint2(pack2bf(a.x, a.y), pack2bf(a.z, a.w));
            *(uint2*)(Bb + byo) = make_uint2(pack2bf(b.x, b.y), pack2bf(b.z, b.w));
        }
        __syncthreads();
        #pragma unroll
        for (int kt = 0; kt < 2; ++kt) {
            bf16x8 af[4], bfr[4];
            const int kb = (kt << 6) + ((lane >> 4) << 4);
            #pragma unroll
            for (int q = 0; q < 4; ++q) {
                const int ar = wm * 64 + q * 16 + (lane & 15);
                const int br = wn * 64 + q * 16 + (lane & 15);
                af[q]  = *(const bf16x8*)(Ab + ar * 128 + (kb ^ ((ar & 7) << 4)));
                bfr[q] = *(const bf16x8*)(Bb + br * 128 + (kb ^ ((br & 7) << 4)));
            }
            #pragma unroll
            for (int mt = 0; mt < 4; ++mt)
                #pragma unroll
                for (int nt = 0; nt < 4; ++nt)
                    acc[mt][nt] = __builtin_amdgcn_mfma_f32_16x16x32_bf16(
                        af[mt], bfr[nt], acc[mt][nt], 0, 0, 0);
        }
    }

    #pragma unroll
    for (int nt = 0; nt < 4; ++nt) {
        const int n = n0 + wn * 64 + nt * 16 + (lane & 15);
        const float bias = bx[n] + bh[n];
        #pragma unroll
        for (int mt = 0; mt < 4; ++mt) {
            const int mb = m0 + wm * 64 + mt * 16 + ((lane >> 4) << 2);
            #pragma unroll
            for (int i = 0; i < 4; ++i)
                out[(size_t)(mb + i) * 1024 + n] = acc[mt][nt][i] + bias;
        }
    }
}

// ---------------------------------------------------------------------------
// Phase 2: persistent scan. 8 groups (8 batches) x 2 blocks (512 H-cols).
// Group g = blockIdx&7 (both blocks on XCD g under %8 round-robin; heuristic
// only -- agent fallback preserves correctness). b = blockIdx>>3 selects col
// half. 1024 threads = 16 waves: wq=wid>>1 (64-col set), kh=wid&1 (K half:
// 0 = own cols [already in local LDS from previous step], 1 = partner cols
// [polled from global]).  Fan-in = ONE partner block; own-half MFMA runs
// concurrently with the partner poll.
// h exchange: tagged words (bf16(h)<<16 | (t+2)) in d_ws, relaxed agent
// atomics (word-granular value+tag -> fence-free).
// ---------------------------------------------------------------------------
__global__ __launch_bounds__(1024, 1) void rnn_scan(
    const float* __restrict__ h0, const float* __restrict__ Wh,
    float* __restrict__ out, float* __restrict__ hfin,
    uint32_t* __restrict__ hbuf)   // [2][64][1024]
{
    // 8 rows x 512 bf16, stride 1040B (pad 16 -> row bank-shift 4, conflict-free)
    __shared__ __align__(16) uint8_t hOwn[8 * 1040];
    __shared__ __align__(16) uint8_t hPar[8 * 1040];
    __shared__ __align__(16) float   pbuf[8][4][32][4];   // partner-half partials

    const int tid  = threadIdx.x;
    const int lane = tid & 63;
    const int wid  = tid >> 6;          // 0..15
    const int wq   = wid >> 1;          // 0..7: 64-col set
    const int kh   = wid & 1;           // 0 = own K half, 1 = partner K half
    const int g    = (int)blockIdx.x & 7;
    const int b    = (int)blockIdx.x >> 3;
    const int gb0  = g * 8;             // batch base
    const int cb   = b * 512;           // own col base
    const int pcb  = 512 - cb;          // partner col base
    const int r4   = ((lane >> 4) & 1) << 2;  // batch sub-base for C rows (lane<32)

    // --- Wh B-fragments: 4 col-tiles x 16 k-chunks over this wave's K half
    bf16x8 whf[4][16];
    {
        const int kb0   = kh ? pcb : cb;
        const int ocol0 = cb + wq * 64 + (lane & 15);
        #pragma unroll
        for (int ct = 0; ct < 4; ++ct) {
            const float* wp = Wh + (size_t)(ocol0 + ct * 16) * 1024 + kb0 + ((lane >> 4) << 3);
            #pragma unroll
            for (int kc = 0; kc < 16; ++kc) {
                const float4 w0 = *(const float4*)(wp + kc * 32);
                const float4 w1 = *(const float4*)(wp + kc * 32 + 4);
                bf16x8 f;
                f[0] = (short)f2bf(w0.x); f[1] = (short)f2bf(w0.y);
                f[2] = (short)f2bf(w0.z); f[3] = (short)f2bf(w0.w);
                f[4] = (short)f2bf(w1.x); f[5] = (short)f2bf(w1.y);
                f[6] = (short)f2bf(w1.z); f[7] = (short)f2bf(w1.w);
                whf[ct][kc] = f;
            }
        }
    }

    uint32_t* const hbE = hbuf;               // parity 0
    uint32_t* const hbO = hbuf + 64 * 1024;   // parity 1

    // --- init: publish own slice of h0 (tag 1, parity 0) + fill own-LDS
    #pragma unroll
    for (int p = 0; p < 4; ++p) {
        const int li = tid + p * 1024;        // 0..4095
        const int bt = li >> 9;               // 0..7
        const int cl = li & 511;
        const uint32_t u = f2bf(h0[(size_t)(gb0 + bt) * 1024 + cb + cl]);
        __hip_atomic_store(&hbE[(gb0 + bt) * 1024 + cb + cl], (u << 16) | 1u,
                           __ATOMIC_RELAXED, __HIP_MEMORY_SCOPE_AGENT);
        *(uint16_t*)(hOwn + bt * 1040 + cl * 2) = (uint16_t)u;
    }
    __syncthreads();

    for (int t = 0; t < 512; ++t) {
        uint32_t* const src = (t & 1) ? hbO : hbE;
        uint32_t* const dst = (t & 1) ? hbE : hbO;
        const uint32_t exptag = (uint32_t)(t + 1);
        const uint32_t ntag   = exptag + 1;

        f32x4 acc[4];
        #pragma unroll
        for (int ct = 0; ct < 4; ++ct) acc[ct] = (f32x4){0.f, 0.f, 0.f, 0.f};
        float xpv[4][4];

        const int abase = (lane & 7) * 1040 + ((lane >> 4) << 4);

        if (kh) {
            // --- poll partner half: 8 batches x 512 cols, 8 words/thread
            const int tix = wq * 64 + lane;   // 0..511 across kh=1 threads
            uint32_t v[8];
            #pragma unroll
            for (int p = 0; p < 8; ++p)
                v[p] = ld_sc0(&src[(gb0 + p) * 1024 + pcb + tix]);
            asm volatile("s_waitcnt vmcnt(0)" ::: "memory");
            __builtin_amdgcn_sched_barrier(0);
            int rounds = 0;
            while (true) {
                bool ok = true;
                #pragma unroll
                for (int p = 0; p < 8; ++p) ok &= ((v[p] & 0xFFFFu) == exptag);
                if (ok) break;
                ++rounds;
                if (rounds <= 3) {
                    #pragma unroll
                    for (int p = 0; p < 8; ++p)
                        v[p] = ld_sc0(&src[(gb0 + p) * 1024 + pcb + tix]);
                    asm volatile("s_waitcnt vmcnt(0)" ::: "memory");
                    __builtin_amdgcn_sched_barrier(0);
                } else {
                    __builtin_amdgcn_s_sleep(1);
                    #pragma unroll
                    for (int p = 0; p < 8; ++p)
                        v[p] = __hip_atomic_load(&src[(gb0 + p) * 1024 + pcb + tix],
                                                 __ATOMIC_RELAXED, __HIP_MEMORY_SCOPE_AGENT);
                }
            }
            #pragma unroll
            for (int p = 0; p < 8; ++p)
                *(uint16_t*)(hPar + p * 1040 + tix * 2) = (uint16_t)(v[p] >> 16);
        } else {
            // --- xp prefetch + own-half MFMA (data local since step t-1)
            if (lane < 32) {
                #pragma unroll
                for (int ct = 0; ct < 4; ++ct) {
                    const int col = cb + wq * 64 + ct * 16 + (lane & 15);
                    #pragma unroll
                    for (int i = 0; i < 4; ++i)
                        xpv[ct][i] = out[((size_t)(gb0 + r4 + i) * 512 + t) * 1024 + col];
                }
            }
            #pragma unroll
            for (int kc = 0; kc < 16; ++kc) {
                const bf16x8 af = *(const bf16x8*)(hOwn + abase + kc * 64);
                acc[0] = __builtin_amdgcn_mfma_f32_16x16x32_bf16(af, whf[0][kc], acc[0], 0, 0, 0);
                acc[1] = __builtin_amdgcn_mfma_f32_16x16x32_bf16(af, whf[1][kc], acc[1], 0, 0, 0);
                acc[2] = __builtin_amdgcn_mfma_f32_16x16x32_bf16(af, whf[2][kc], acc[2], 0, 0, 0);
                acc[3] = __builtin_amdgcn_mfma_f32_16x16x32_bf16(af, whf[3][kc], acc[3], 0, 0, 0);
            }
        }
        __syncthreads();   // hPar fully written

        if (kh) {
            // --- partner-half MFMA, then export partials
            #pragma unroll
            for (int kc = 0; kc < 16; ++kc) {
                const bf16x8 af = *(const bf16x8*)(hPar + abase + kc * 64);
                acc[0] = __builtin_amdgcn_mfma_f32_16x16x32_bf16(af, whf[0][kc], acc[0], 0, 0, 0);
                acc[1] = __builtin_amdgcn_mfma_f32_16x16x32_bf16(af, whf[1][kc], acc[1], 0, 0, 0);
                acc[2] = __builtin_amdgcn_mfma_f32_16x16x32_bf16(af, whf[2][kc], acc[2], 0, 0, 0);
                acc[3] = __builtin_amdgcn_mfma_f32_16x16x32_bf16(af, whf[3][kc], acc[3], 0, 0, 0);
            }
            if (lane < 32) {
                #pragma unroll
                for (int ct = 0; ct < 4; ++ct)
                    *(f32x4*)&pbuf[wq][ct][lane][0] = acc[ct];
            }
        }
        __syncthreads();   // pbuf ready

        if (!kh && lane < 32) {
            // --- finalize: pre = own + partner + xp; publish h first
            uint32_t hu[4][4];
            #pragma unroll
            for (int ct = 0; ct < 4; ++ct) {
                const f32x4 part = *(const f32x4*)&pbuf[wq][ct][lane][0];
                #pragma unroll
                for (int i = 0; i < 4; ++i) {
                    const float pre = acc[ct][i] + part[i] + xpv[ct][i];
                    xpv[ct][i] = pre;                 // reuse as pre
                    hu[ct][i]  = f2bf(fast_tanh(pre));
                }
            }
            if (t < 511) {
                #pragma unroll
                for (int ct = 0; ct < 4; ++ct) {
                    const int col = cb + wq * 64 + ct * 16 + (lane & 15);
                    #pragma unroll
                    for (int i = 0; i < 4; ++i)
                        __hip_atomic_store(&dst[(gb0 + r4 + i) * 1024 + col],
                                           (hu[ct][i] << 16) | ntag,
                                           __ATOMIC_RELAXED, __HIP_MEMORY_SCOPE_AGENT);
                }
            }
            #pragma unroll
            for (int ct = 0; ct < 4; ++ct) {
                const int col = cb + wq * 64 + ct * 16 + (lane & 15);
                #pragma unroll
                for (int i = 0; i < 4; ++i) {
                    out[((size_t)(gb0 + r4 + i) * 512 + t) * 1024 + col] = xpv[ct][i];
                    *(uint16_t*)(hOwn + (r4 + i) * 1040 + (col - cb) * 2) = (uint16_t)hu[ct][i];
                    if (t == 511)
                        hfin[(size_t)(gb0 + r4 + i) * 1024 + col] = fast_tanh(xpv[ct][i]);
                }
            }
        }
        __syncthreads();   // hOwn stable before next step's phase A
    }
}

// ---------------------------------------------------------------------------
extern "C" void kernel_launch(void* const* d_in, const int* in_sizes, int n_in,
                              void* d_out, int out_size, void* d_ws, size_t ws_size,
                              hipStream_t stream) {
    const float* x   = (const float*)d_in[0];   // [64,512,512]
    const float* h0_ = (const float*)d_in[1];   // [64,1024]
    const float* Wx  = (const float*)d_in[2];   // [1024,512]
    const float* bx  = (const float*)d_in[3];   // [1024]
    const float* Wh  = (const float*)d_in[4];   // [1024,1024]
    const float* bh  = (const float*)d_in[5];   // [1024]
    float* out  = (float*)d_out;                         // [64,512,1024] pre
    float* hfin = out + (size_t)64 * 512 * 1024;         // [64,1024]
    uint32_t* hbuf = (uint32_t*)d_ws;                    // 2*64*1024 u32 = 512 KB

    // invalidate all tags (0xFFFF matches no step tag 1..513)
    hipMemsetAsync(d_ws, 0xFF, (size_t)2 * 64 * 1024 * sizeof(uint32_t), stream);

    xproj_gemm<<<dim3(2048), dim3(256), 0, stream>>>(x, Wx, bx, bh, out);
    rnn_scan<<<dim3(16), dim3(1024), 0, stream>>>(h0_, Wh, out, hfin, hbuf);
}

// Round 5
// 13068.831 us; speedup vs baseline: 1.0774x; 1.0774x over previous
//
#include <hip/hip_runtime.h>
#include <stdint.h>

// MyVanillaRNN: B=64, T=512, INPUT=512, HIDDEN=1024
// out = concat( pre[B,T,H] (f32), h_final[B,H] (f32) )

typedef __attribute__((ext_vector_type(8))) short bf16x8;
typedef __attribute__((ext_vector_type(4))) float f32x4;

__device__ __forceinline__ uint32_t f2bf(float f) {
    union { float f; uint32_t u; } v; v.f = f;
    return (v.u + 0x7FFFu + ((v.u >> 16) & 1u)) >> 16;   // RNE
}
__device__ __forceinline__ uint32_t pack2bf(float a, float b) {
    return f2bf(a) | (f2bf(b) << 16);
}
__device__ __forceinline__ float fast_tanh(float x) {
    const float xc = fminf(fmaxf(x, -15.f), 15.f);
    const float e  = __expf(2.f * xc);
    return (e - 1.f) * __builtin_amdgcn_rcpf(e + 1.f);
}
// L1-bypassing load (hits the XCD's shared L2). Same-XCD normal stores are
// visible here at L2 latency. Cross-XCD freshness NOT guaranteed -> caller
// falls back to agent-scope loads on the slow buffer for liveness.
__device__ __forceinline__ uint32_t ld_sc0(const uint32_t* p) {
    uint32_t v;
    asm volatile("global_load_dword %0, %1, off sc0"
                 : "=v"(v) : "v"((uint64_t)(uintptr_t)p));
    return v;
}

// ---------------------------------------------------------------------------
// Phase 1: out[m][n] = sum_k x[m][k]*Wx[n][k] + bx[n] + bh[n]
// M=32768, N=1024, K=512.  128x128 tile, BK=64, 4 waves, bf16 MFMA.
// ---------------------------------------------------------------------------
__global__ __launch_bounds__(256) void xproj_gemm(
    const float* __restrict__ x, const float* __restrict__ Wx,
    const float* __restrict__ bx, const float* __restrict__ bh,
    float* __restrict__ out)
{
    __shared__ __align__(16) uint8_t Ab[128 * 128];
    __shared__ __align__(16) uint8_t Bb[128 * 128];

    const int tid  = threadIdx.x;
    const int lane = tid & 63;
    const int wid  = tid >> 6;
    const int wm = wid >> 1, wn = wid & 1;
    const int m0 = (int)(blockIdx.x >> 3) * 128;
    const int n0 = (int)(blockIdx.x & 7) * 128;

    f32x4 acc[4][4];
    #pragma unroll
    for (int i = 0; i < 4; ++i)
        #pragma unroll
        for (int j = 0; j < 4; ++j) acc[i][j] = (f32x4){0.f, 0.f, 0.f, 0.f};

    const int sr = tid >> 4;
    const int sk = (tid & 15) << 2;

    for (int k0 = 0; k0 < 512; k0 += 64) {
        __syncthreads();
        #pragma unroll
        for (int p = 0; p < 8; ++p) {
            const int r = sr + p * 16;
            const float4 a = *(const float4*)(x  + (size_t)(m0 + r) * 512 + k0 + sk);
            const float4 b = *(const float4*)(Wx + (size_t)(n0 + r) * 512 + k0 + sk);
            const int byo = r * 128 + ((sk << 1) ^ ((r & 7) << 4));
            *(uint2*)(Ab + byo) = make_uint2(pack2bf(a.x, a.y), pack2bf(a.z, a.w));
            *(uint2*)(Bb + byo) = make_uint2(pack2bf(b.x, b.y), pack2bf(b.z, b.w));
        }
        __syncthreads();
        #pragma unroll
        for (int kt = 0; kt < 2; ++kt) {
            bf16x8 af[4], bfr[4];
            const int kb = (kt << 6) + ((lane >> 4) << 4);
            #pragma unroll
            for (int q = 0; q < 4; ++q) {
                const int ar = wm * 64 + q * 16 + (lane & 15);
                const int br = wn * 64 + q * 16 + (lane & 15);
                af[q]  = *(const bf16x8*)(Ab + ar * 128 + (kb ^ ((ar & 7) << 4)));
                bfr[q] = *(const bf16x8*)(Bb + br * 128 + (kb ^ ((br & 7) << 4)));
            }
            #pragma unroll
            for (int mt = 0; mt < 4; ++mt)
                #pragma unroll
                for (int nt = 0; nt < 4; ++nt)
                    acc[mt][nt] = __builtin_amdgcn_mfma_f32_16x16x32_bf16(
                        af[mt], bfr[nt], acc[mt][nt], 0, 0, 0);
        }
    }

    #pragma unroll
    for (int nt = 0; nt < 4; ++nt) {
        const int n = n0 + wn * 64 + nt * 16 + (lane & 15);
        const float bias = bx[n] + bh[n];
        #pragma unroll
        for (int mt = 0; mt < 4; ++mt) {
            const int mb = m0 + wm * 64 + mt * 16 + ((lane >> 4) << 2);
            #pragma unroll
            for (int i = 0; i < 4; ++i)
                out[(size_t)(mb + i) * 1024 + n] = acc[mt][nt][i] + bias;
        }
    }
}

// ---------------------------------------------------------------------------
// Phase 2: persistent scan. 8 groups (8 batches) x 8 blocks (128 H-cols).
// Group g = blockIdx&7 -> all 8 blocks of a group on XCD g under %8
// round-robin (perf heuristic; correctness preserved by the slow path).
// Block nb = blockIdx>>3: cols [128nb,+128). Wave w: cols [..+16w,+16),
// full K=1024, Wh fragments register-resident (128 VGPR).
// h exchange, tagged words (bf16<<16 | (t+1)):
//   FAST: plain global stores into fbuf  -> land in the XCD's shared L2;
//         polled with sc0 loads (L2 hit, ~300ns same-XCD visibility).
//   SLOW: agent-scope atomic stores into sbuf -> fabric-coherent; polled
//         as fallback after 32 fast rounds (guaranteed liveness).
// Own 128 cols skip global entirely (parity-double-buffered LDS tile).
// xp is software-pipelined one step ahead so the poll's s_waitcnt never
// waits on an HBM load (round-3 bug).
// ---------------------------------------------------------------------------
__global__ __launch_bounds__(512, 2) void rnn_scan(
    const float* __restrict__ h0, const float* __restrict__ Wh,
    float* __restrict__ out, float* __restrict__ hfin,
    uint32_t* __restrict__ fbuf, uint32_t* __restrict__ sbuf, int dual)
{
    __shared__ __align__(16) uint8_t htile[2][8 * 2048]; // parity x 8 batches x 1024 bf16 (swizzled)

    const int tid  = threadIdx.x;
    const int lane = tid & 63;
    const int wid  = tid >> 6;          // 0..7
    const int g    = (int)blockIdx.x & 7;
    const int nb   = (int)blockIdx.x >> 3;
    const int gb0  = g * 8;             // batch base
    const int col  = nb * 128 + wid * 16 + (lane & 15);   // own output col
    const int r4b  = ((lane >> 4) & 1) << 2;              // 0/4 batch sub-base (lane<32)

    // --- Wh B-fragments: own col, full K. frag kt elem j <-> k=kt*32+(lane>>4)*8+j
    bf16x8 whf[32];
    {
        const float* wp = Wh + (size_t)col * 1024 + ((lane >> 4) << 3);
        #pragma unroll
        for (int kt = 0; kt < 32; ++kt) {
            const float4 w0 = *(const float4*)(wp + kt * 32);
            const float4 w1 = *(const float4*)(wp + kt * 32 + 4);
            bf16x8 f;
            f[0] = (short)f2bf(w0.x); f[1] = (short)f2bf(w0.y);
            f[2] = (short)f2bf(w0.z); f[3] = (short)f2bf(w0.w);
            f[4] = (short)f2bf(w1.x); f[5] = (short)f2bf(w1.y);
            f[6] = (short)f2bf(w1.z); f[7] = (short)f2bf(w1.w);
            whf[kt] = f;
        }
    }

    // --- init: publish own slice of h0 (tag 1, parity 0) + own LDS fill
    {
        const int colI = nb * 128 + lane * 2;   // two adjacent own cols
        const uint32_t u0 = f2bf(h0[(size_t)(gb0 + wid) * 1024 + colI]);
        const uint32_t u1 = f2bf(h0[(size_t)(gb0 + wid) * 1024 + colI + 1]);
        const int idx = (gb0 + wid) * 1024 + colI;
        if (dual) {
            ((volatile uint32_t*)fbuf)[idx]     = (u0 << 16) | 1u;
            ((volatile uint32_t*)fbuf)[idx + 1] = (u1 << 16) | 1u;
            __hip_atomic_store(&sbuf[idx],     (u0 << 16) | 1u, __ATOMIC_RELAXED, __HIP_MEMORY_SCOPE_AGENT);
            __hip_atomic_store(&sbuf[idx + 1], (u1 << 16) | 1u, __ATOMIC_RELAXED, __HIP_MEMORY_SCOPE_AGENT);
        } else {
            __hip_atomic_store(&fbuf[idx],     (u0 << 16) | 1u, __ATOMIC_RELAXED, __HIP_MEMORY_SCOPE_AGENT);
            __hip_atomic_store(&fbuf[idx + 1], (u1 << 16) | 1u, __ATOMIC_RELAXED, __HIP_MEMORY_SCOPE_AGENT);
        }
        *(uint32_t*)(htile[0] + wid * 2048 + ((colI * 2) ^ (wid << 4))) = u0 | (u1 << 16);
    }

    // --- poll indices: 7 remote blocks x 2 words; pb==wid, cols lane*2,+1
    const int pb  = wid;
    const int pc0 = lane * 2;
    int ridx[7];
    #pragma unroll
    for (int r = 0; r < 7; ++r) {
        const int rbk = (nb + 1 + r) & 7;
        ridx[r] = (gb0 + pb) * 1024 + rbk * 128 + pc0;
    }

    // --- xp preload for t=0
    float xpv[4];
    if (lane < 32) {
        #pragma unroll
        for (int i = 0; i < 4; ++i)
            xpv[i] = out[((size_t)(gb0 + r4b + i) * 512 + 0) * 1024 + col];
    }

    for (int t = 0; t < 512; ++t) {
        const int cur = t & 1;
        uint32_t* const fsrc = fbuf + cur * 65536;
        uint32_t* const fdst = fbuf + (cur ^ 1) * 65536;
        uint32_t* const ssrc = sbuf + cur * 65536;
        uint32_t* const sdst = sbuf + (cur ^ 1) * 65536;
        const uint32_t exptag = (uint32_t)(t + 1);
        const uint32_t ntag   = exptag + 1;

        // --- phase A: poll the 7 remote blocks' slices (fast L2 path)
        uint32_t v[14];
        #pragma unroll
        for (int r = 0; r < 7; ++r) {
            v[2 * r]     = ld_sc0(&fsrc[ridx[r]]);
            v[2 * r + 1] = ld_sc0(&fsrc[ridx[r] + 1]);
        }
        asm volatile("s_waitcnt vmcnt(0)" ::: "memory");
        __builtin_amdgcn_sched_barrier(0);
        int rounds = 0;
        while (true) {
            bool ok = true;
            #pragma unroll
            for (int p = 0; p < 14; ++p) ok &= ((v[p] & 0xFFFFu) == exptag);
            if (ok) break;
            ++rounds;
            if (rounds < 32) {
                #pragma unroll
                for (int r = 0; r < 7; ++r) {
                    v[2 * r]     = ld_sc0(&fsrc[ridx[r]]);
                    v[2 * r + 1] = ld_sc0(&fsrc[ridx[r] + 1]);
                }
                asm volatile("s_waitcnt vmcnt(0)" ::: "memory");
                __builtin_amdgcn_sched_barrier(0);
            } else {
                __builtin_amdgcn_s_sleep(2);
                #pragma unroll
                for (int r = 0; r < 7; ++r) {
                    v[2 * r]     = __hip_atomic_load(&ssrc[ridx[r]],     __ATOMIC_RELAXED, __HIP_MEMORY_SCOPE_AGENT);
                    v[2 * r + 1] = __hip_atomic_load(&ssrc[ridx[r] + 1], __ATOMIC_RELAXED, __HIP_MEMORY_SCOPE_AGENT);
                }
            }
        }
        // stage remote h into this parity's LDS tile
        #pragma unroll
        for (int r = 0; r < 7; ++r) {
            const int rbk = (nb + 1 + r) & 7;
            const int c0  = rbk * 128 + pc0;
            const uint32_t pk = (v[2 * r] >> 16) | (v[2 * r + 1] & 0xFFFF0000u);
            *(uint32_t*)(htile[cur] + pb * 2048 + ((c0 * 2) ^ (pb << 4))) = pk;
        }
        __syncthreads();   // htile[cur] complete (remote staged + own from t-1)

        // --- xp prefetch for NEXT step (off the poll's critical path)
        float xnext[4];
        if (lane < 32 && t < 511) {
            #pragma unroll
            for (int i = 0; i < 4; ++i)
                xnext[i] = out[((size_t)(gb0 + r4b + i) * 512 + (t + 1)) * 1024 + col];
        }

        // --- phase B: acc = h . Wh[col]^T over full K, 4 interleaved chains
        f32x4 a0 = (f32x4){0.f,0.f,0.f,0.f}, a1 = a0, a2 = a0, a3 = a0;
        {
            const int b_  = lane & 7;
            const int kbx = (lane >> 4) << 4;
            const int swz = b_ << 4;
            const uint8_t* hb = htile[cur] + b_ * 2048;
            #pragma unroll
            for (int kt = 0; kt < 32; kt += 4) {
                const bf16x8 f0 = *(const bf16x8*)(hb + (((kt    ) * 64 + kbx) ^ swz));
                const bf16x8 f1 = *(const bf16x8*)(hb + (((kt + 1) * 64 + kbx) ^ swz));
                const bf16x8 f2 = *(const bf16x8*)(hb + (((kt + 2) * 64 + kbx) ^ swz));
                const bf16x8 f3 = *(const bf16x8*)(hb + (((kt + 3) * 64 + kbx) ^ swz));
                a0 = __builtin_amdgcn_mfma_f32_16x16x32_bf16(f0, whf[kt    ], a0, 0, 0, 0);
                a1 = __builtin_amdgcn_mfma_f32_16x16x32_bf16(f1, whf[kt + 1], a1, 0, 0, 0);
                a2 = __builtin_amdgcn_mfma_f32_16x16x32_bf16(f2, whf[kt + 2], a2, 0, 0, 0);
                a3 = __builtin_amdgcn_mfma_f32_16x16x32_bf16(f3, whf[kt + 3], a3, 0, 0, 0);
            }
        }

        // --- phase C: finalize; publish h (fast then slow), then out[]
        if (lane < 32) {
            float pre[4];
            uint32_t hu[4];
            #pragma unroll
            for (int i = 0; i < 4; ++i) {
                pre[i] = ((a0[i] + a1[i]) + (a2[i] + a3[i])) + xpv[i];
                hu[i]  = f2bf(fast_tanh(pre[i]));
            }
            if (t < 511) {
                if (dual) {
                    #pragma unroll
                    for (int i = 0; i < 4; ++i)
                        ((volatile uint32_t*)fdst)[(gb0 + r4b + i) * 1024 + col] = (hu[i] << 16) | ntag;
                    #pragma unroll
                    for (int i = 0; i < 4; ++i)
                        __hip_atomic_store(&sdst[(gb0 + r4b + i) * 1024 + col], (hu[i] << 16) | ntag,
                                           __ATOMIC_RELAXED, __HIP_MEMORY_SCOPE_AGENT);
                } else {
                    #pragma unroll
                    for (int i = 0; i < 4; ++i)
                        __hip_atomic_store(&fdst[(gb0 + r4b + i) * 1024 + col], (hu[i] << 16) | ntag,
                                           __ATOMIC_RELAXED, __HIP_MEMORY_SCOPE_AGENT);
                }
                // own slice -> next parity's LDS tile (never crosses global)
                #pragma unroll
                for (int i = 0; i < 4; ++i)
                    *(uint16_t*)(htile[cur ^ 1] + (r4b + i) * 2048 + ((col * 2) ^ ((r4b + i) << 4))) = (uint16_t)hu[i];
            }
            #pragma unroll
            for (int i = 0; i < 4; ++i) {
                out[((size_t)(gb0 + r4b + i) * 512 + t) * 1024 + col] = pre[i];
                if (t == 511) {
                    union { uint32_t u; float f; } hf; hf.u = hu[i] << 16;
                    hfin[(size_t)(gb0 + r4b + i) * 1024 + col] = hf.f;
                }
            }
            #pragma unroll
            for (int i = 0; i < 4; ++i) xpv[i] = xnext[i];
        }
    }
}

// ---------------------------------------------------------------------------
extern "C" void kernel_launch(void* const* d_in, const int* in_sizes, int n_in,
                              void* d_out, int out_size, void* d_ws, size_t ws_size,
                              hipStream_t stream) {
    const float* x   = (const float*)d_in[0];   // [64,512,512]
    const float* h0_ = (const float*)d_in[1];   // [64,1024]
    const float* Wx  = (const float*)d_in[2];   // [1024,512]
    const float* bx  = (const float*)d_in[3];   // [1024]
    const float* Wh  = (const float*)d_in[4];   // [1024,1024]
    const float* bh  = (const float*)d_in[5];   // [1024]
    float* out  = (float*)d_out;                         // [64,512,1024] pre
    float* hfin = out + (size_t)64 * 512 * 1024;         // [64,1024]

    const size_t words_half = (size_t)2 * 64 * 1024;     // one buffer: [2][64][1024]
    const size_t need_dual  = 2 * words_half * sizeof(uint32_t);   // 1 MiB
    const int dual = (ws_size >= need_dual) ? 1 : 0;
    uint32_t* fbuf = (uint32_t*)d_ws;
    uint32_t* sbuf = dual ? fbuf + words_half : fbuf;

    hipMemsetAsync(d_ws, 0xFF,
                   (dual ? need_dual : words_half * sizeof(uint32_t)), stream);

    xproj_gemm<<<dim3(2048), dim3(256), 0, stream>>>(x, Wx, bx, bh, out);
    rnn_scan<<<dim3(64), dim3(512), 0, stream>>>(h0_, Wh, out, hfin, fbuf, sbuf, dual);
}

// Round 6
// 1562.121 us; speedup vs baseline: 9.0139x; 8.3661x over previous
//
#include <hip/hip_runtime.h>
#include <stdint.h>

// MyVanillaRNN: B=64, T=512, INPUT=512, HIDDEN=1024
// out = concat( pre[B,T,H] (f32), h_final[B,H] (f32) )

typedef __attribute__((ext_vector_type(8))) short bf16x8;
typedef __attribute__((ext_vector_type(4))) float f32x4;

__device__ __forceinline__ uint32_t f2bf(float f) {
    union { float f; uint32_t u; } v; v.f = f;
    return (v.u + 0x7FFFu + ((v.u >> 16) & 1u)) >> 16;   // RNE
}
__device__ __forceinline__ uint32_t pack2bf(float a, float b) {
    return f2bf(a) | (f2bf(b) << 16);
}
__device__ __forceinline__ float fast_tanh(float x) {
    const float xc = fminf(fmaxf(x, -15.f), 15.f);
    const float e  = __expf(2.f * xc);
    return (e - 1.f) * __builtin_amdgcn_rcpf(e + 1.f);
}

// ---------------------------------------------------------------------------
// Phase 1: out[m][n] = sum_k x[m][k]*Wx[n][k] + bx[n] + bh[n]
// M=32768, N=1024, K=512.  128x128 tile, BK=64, 4 waves, bf16 MFMA.
// ---------------------------------------------------------------------------
__global__ __launch_bounds__(256) void xproj_gemm(
    const float* __restrict__ x, const float* __restrict__ Wx,
    const float* __restrict__ bx, const float* __restrict__ bh,
    float* __restrict__ out)
{
    __shared__ __align__(16) uint8_t Ab[128 * 128];
    __shared__ __align__(16) uint8_t Bb[128 * 128];

    const int tid  = threadIdx.x;
    const int lane = tid & 63;
    const int wid  = tid >> 6;
    const int wm = wid >> 1, wn = wid & 1;
    const int m0 = (int)(blockIdx.x >> 3) * 128;
    const int n0 = (int)(blockIdx.x & 7) * 128;

    f32x4 acc[4][4];
    #pragma unroll
    for (int i = 0; i < 4; ++i)
        #pragma unroll
        for (int j = 0; j < 4; ++j) acc[i][j] = (f32x4){0.f, 0.f, 0.f, 0.f};

    const int sr = tid >> 4;
    const int sk = (tid & 15) << 2;

    for (int k0 = 0; k0 < 512; k0 += 64) {
        __syncthreads();
        #pragma unroll
        for (int p = 0; p < 8; ++p) {
            const int r = sr + p * 16;
            const float4 a = *(const float4*)(x  + (size_t)(m0 + r) * 512 + k0 + sk);
            const float4 b = *(const float4*)(Wx + (size_t)(n0 + r) * 512 + k0 + sk);
            const int byo = r * 128 + ((sk << 1) ^ ((r & 7) << 4));
            *(uint2*)(Ab + byo) = make_uint2(pack2bf(a.x, a.y), pack2bf(a.z, a.w));
            *(uint2*)(Bb + byo) = make_uint2(pack2bf(b.x, b.y), pack2bf(b.z, b.w));
        }
        __syncthreads();
        #pragma unroll
        for (int kt = 0; kt < 2; ++kt) {
            bf16x8 af[4], bfr[4];
            const int kb = (kt << 6) + ((lane >> 4) << 4);
            #pragma unroll
            for (int q = 0; q < 4; ++q) {
                const int ar = wm * 64 + q * 16 + (lane & 15);
                const int br = wn * 64 + q * 16 + (lane & 15);
                af[q]  = *(const bf16x8*)(Ab + ar * 128 + (kb ^ ((ar & 7) << 4)));
                bfr[q] = *(const bf16x8*)(Bb + br * 128 + (kb ^ ((br & 7) << 4)));
            }
            #pragma unroll
            for (int mt = 0; mt < 4; ++mt)
                #pragma unroll
                for (int nt = 0; nt < 4; ++nt)
                    acc[mt][nt] = __builtin_amdgcn_mfma_f32_16x16x32_bf16(
                        af[mt], bfr[nt], acc[mt][nt], 0, 0, 0);
        }
    }

    #pragma unroll
    for (int nt = 0; nt < 4; ++nt) {
        const int n = n0 + wn * 64 + nt * 16 + (lane & 15);
        const float bias = bx[n] + bh[n];
        #pragma unroll
        for (int mt = 0; mt < 4; ++mt) {
            const int mb = m0 + wm * 64 + mt * 16 + ((lane >> 4) << 2);
            #pragma unroll
            for (int i = 0; i < 4; ++i)
                out[(size_t)(mb + i) * 1024 + n] = acc[mt][nt][i] + bias;
        }
    }
}

// ---------------------------------------------------------------------------
// Phase 2: persistent scan. 8 groups (8 batches) x 8 blocks (128 H-cols).
// Block = 512 thr (8 waves); wave w: cols [128nb+16w,+16), full K=1024,
// Wh register-resident (128 VGPR).
// LDS padded to ~98KB -> exactly 1 block/CU (kills spin interference from
// co-resident blocks).
// h exchange: tagged words (bf16(h)<<16 | (t+1)) in d_ws; publish = relaxed
// agent-scope atomic store (fabric-coherent, the only path measured to
// deliver fresh data); poll = relaxed agent-scope atomic loads EVERY round,
// tight loop (no sleep, no sc0 stale-L2 rounds -- rounds 3/5 lesson).
// Own 128 cols never cross global (parity double-buffered LDS tile).
// xp software-pipelined one step ahead so the poll never waits on HBM.
// ---------------------------------------------------------------------------
__global__ __launch_bounds__(512, 1) void rnn_scan(
    const float* __restrict__ h0, const float* __restrict__ Wh,
    float* __restrict__ out, float* __restrict__ hfin,
    uint32_t* __restrict__ hbuf)   // [2][64][1024] tagged words
{
    // only rows 0..7 (x2048B) of each parity half are used; the rest is
    // deliberate padding to force LDS_Block_Size > 80KB => 1 block/CU.
    __shared__ __align__(16) uint8_t htile[2][49152];

    const int tid  = threadIdx.x;
    const int lane = tid & 63;
    const int wid  = tid >> 6;          // 0..7
    const int g    = (int)blockIdx.x & 7;
    const int nb   = (int)blockIdx.x >> 3;
    const int gb0  = g * 8;             // batch base
    const int col  = nb * 128 + wid * 16 + (lane & 15);   // own output col
    const int r4b  = ((lane >> 4) & 1) << 2;              // 0/4 batch sub-base

    // --- Wh B-fragments: own col, full K. frag kt elem j <-> k=kt*32+(lane>>4)*8+j
    bf16x8 whf[32];
    {
        const float* wp = Wh + (size_t)col * 1024 + ((lane >> 4) << 3);
        #pragma unroll
        for (int kt = 0; kt < 32; ++kt) {
            const float4 w0 = *(const float4*)(wp + kt * 32);
            const float4 w1 = *(const float4*)(wp + kt * 32 + 4);
            bf16x8 f;
            f[0] = (short)f2bf(w0.x); f[1] = (short)f2bf(w0.y);
            f[2] = (short)f2bf(w0.z); f[3] = (short)f2bf(w0.w);
            f[4] = (short)f2bf(w1.x); f[5] = (short)f2bf(w1.y);
            f[6] = (short)f2bf(w1.z); f[7] = (short)f2bf(w1.w);
            whf[kt] = f;
        }
    }

    // --- init: publish own slice of h0 (tag 1, parity 0) + own LDS fill
    {
        const int colI = nb * 128 + lane * 2;   // two adjacent own cols
        const uint32_t u0 = f2bf(h0[(size_t)(gb0 + wid) * 1024 + colI]);
        const uint32_t u1 = f2bf(h0[(size_t)(gb0 + wid) * 1024 + colI + 1]);
        const int idx = (gb0 + wid) * 1024 + colI;
        __hip_atomic_store(&hbuf[idx],     (u0 << 16) | 1u, __ATOMIC_RELAXED, __HIP_MEMORY_SCOPE_AGENT);
        __hip_atomic_store(&hbuf[idx + 1], (u1 << 16) | 1u, __ATOMIC_RELAXED, __HIP_MEMORY_SCOPE_AGENT);
        *(uint32_t*)(htile[0] + wid * 2048 + ((colI * 2) ^ (wid << 4))) = u0 | (u1 << 16);
    }

    // --- poll indices: 7 remote blocks x 2 words; batch row = wid
    const int pb  = wid;
    const int pc0 = lane * 2;
    int ridx[7];
    #pragma unroll
    for (int r = 0; r < 7; ++r) {
        const int rbk = (nb + 1 + r) & 7;
        ridx[r] = (gb0 + pb) * 1024 + rbk * 128 + pc0;
    }

    // --- xp preload for t=0 (all lanes; lanes>=32 mirror lanes<32)
    float xpv[4];
    #pragma unroll
    for (int i = 0; i < 4; ++i)
        xpv[i] = out[((size_t)(gb0 + r4b + i) * 512 + 0) * 1024 + col];

    for (int t = 0; t < 512; ++t) {
        const int cur = t & 1;
        uint32_t* const src = hbuf + cur * 65536;
        uint32_t* const dst = hbuf + (cur ^ 1) * 65536;
        const uint32_t exptag = (uint32_t)(t + 1);
        const uint32_t ntag   = exptag + 1;

        // --- phase A: poll the 7 remote blocks' slices (agent loads, tight)
        uint32_t v[14];
        int rounds = 0;
        while (true) {
            #pragma unroll
            for (int r = 0; r < 7; ++r) {
                v[2 * r]     = __hip_atomic_load(&src[ridx[r]],     __ATOMIC_RELAXED, __HIP_MEMORY_SCOPE_AGENT);
                v[2 * r + 1] = __hip_atomic_load(&src[ridx[r] + 1], __ATOMIC_RELAXED, __HIP_MEMORY_SCOPE_AGENT);
            }
            bool ok = true;
            #pragma unroll
            for (int p = 0; p < 14; ++p) ok &= ((v[p] & 0xFFFFu) == exptag);
            if (ok) break;
            if (++rounds > 256) __builtin_amdgcn_s_sleep(2);   // paranoia only
        }
        // stage remote h into this parity's LDS tile
        #pragma unroll
        for (int r = 0; r < 7; ++r) {
            const int rbk = (nb + 1 + r) & 7;
            const int c0  = rbk * 128 + pc0;
            const uint32_t pk = (v[2 * r] >> 16) | (v[2 * r + 1] & 0xFFFF0000u);
            *(uint32_t*)(htile[cur] + pb * 2048 + ((c0 * 2) ^ (pb << 4))) = pk;
        }
        __syncthreads();   // htile[cur] complete (remote staged + own from t-1)

        // --- xp prefetch for NEXT step (off the poll's critical path)
        float xnext[4];
        if (t < 511) {
            #pragma unroll
            for (int i = 0; i < 4; ++i)
                xnext[i] = out[((size_t)(gb0 + r4b + i) * 512 + (t + 1)) * 1024 + col];
        }

        // --- phase B: acc = h . Wh[col]^T over full K, 4 interleaved chains
        f32x4 a0 = (f32x4){0.f,0.f,0.f,0.f}, a1 = a0, a2 = a0, a3 = a0;
        {
            const int b_  = lane & 7;
            const int kbx = (lane >> 4) << 4;
            const int swz = b_ << 4;
            const uint8_t* hb = htile[cur] + b_ * 2048;
            #pragma unroll
            for (int kt = 0; kt < 32; kt += 4) {
                const bf16x8 f0 = *(const bf16x8*)(hb + (((kt    ) * 64 + kbx) ^ swz));
                const bf16x8 f1 = *(const bf16x8*)(hb + (((kt + 1) * 64 + kbx) ^ swz));
                const bf16x8 f2 = *(const bf16x8*)(hb + (((kt + 2) * 64 + kbx) ^ swz));
                const bf16x8 f3 = *(const bf16x8*)(hb + (((kt + 3) * 64 + kbx) ^ swz));
                a0 = __builtin_amdgcn_mfma_f32_16x16x32_bf16(f0, whf[kt    ], a0, 0, 0, 0);
                a1 = __builtin_amdgcn_mfma_f32_16x16x32_bf16(f1, whf[kt + 1], a1, 0, 0, 0);
                a2 = __builtin_amdgcn_mfma_f32_16x16x32_bf16(f2, whf[kt + 2], a2, 0, 0, 0);
                a3 = __builtin_amdgcn_mfma_f32_16x16x32_bf16(f3, whf[kt + 3], a3, 0, 0, 0);
            }
        }

        // --- phase C: lanes<32 publish h (critical path); lanes>=32 (which
        // hold a duplicate C fragment) write out[] concurrently.
        float pre[4], hn[4];
        #pragma unroll
        for (int i = 0; i < 4; ++i) {
            pre[i] = ((a0[i] + a1[i]) + (a2[i] + a3[i])) + xpv[i];
            hn[i]  = fast_tanh(pre[i]);
        }
        if (lane < 32) {
            if (t < 511) {
                uint32_t hu[4];
                #pragma unroll
                for (int i = 0; i < 4; ++i) hu[i] = f2bf(hn[i]);
                #pragma unroll
                for (int i = 0; i < 4; ++i)
                    __hip_atomic_store(&dst[(gb0 + r4b + i) * 1024 + col], (hu[i] << 16) | ntag,
                                       __ATOMIC_RELAXED, __HIP_MEMORY_SCOPE_AGENT);
                // own slice -> next parity's LDS tile (never crosses global)
                #pragma unroll
                for (int i = 0; i < 4; ++i)
                    *(uint16_t*)(htile[cur ^ 1] + (r4b + i) * 2048 + ((col * 2) ^ ((r4b + i) << 4))) = (uint16_t)hu[i];
            }
        } else {
            #pragma unroll
            for (int i = 0; i < 4; ++i) {
                out[((size_t)(gb0 + r4b + i) * 512 + t) * 1024 + col] = pre[i];
                if (t == 511) hfin[(size_t)(gb0 + r4b + i) * 1024 + col] = hn[i];
            }
        }
        #pragma unroll
        for (int i = 0; i < 4; ++i) xpv[i] = xnext[i];
    }
}

// ---------------------------------------------------------------------------
extern "C" void kernel_launch(void* const* d_in, const int* in_sizes, int n_in,
                              void* d_out, int out_size, void* d_ws, size_t ws_size,
                              hipStream_t stream) {
    const float* x   = (const float*)d_in[0];   // [64,512,512]
    const float* h0_ = (const float*)d_in[1];   // [64,1024]
    const float* Wx  = (const float*)d_in[2];   // [1024,512]
    const float* bx  = (const float*)d_in[3];   // [1024]
    const float* Wh  = (const float*)d_in[4];   // [1024,1024]
    const float* bh  = (const float*)d_in[5];   // [1024]
    float* out  = (float*)d_out;                         // [64,512,1024] pre
    float* hfin = out + (size_t)64 * 512 * 1024;         // [64,1024]
    uint32_t* hbuf = (uint32_t*)d_ws;                    // [2][64][1024] u32 = 512 KB

    // invalidate all tags (0xFFFF matches no step tag 1..513)
    hipMemsetAsync(d_ws, 0xFF, (size_t)2 * 64 * 1024 * sizeof(uint32_t), stream);

    xproj_gemm<<<dim3(2048), dim3(256), 0, stream>>>(x, Wx, bx, bh, out);
    rnn_scan<<<dim3(64), dim3(512), 0, stream>>>(h0_, Wh, out, hfin, hbuf);
}